// Round 2
// baseline (1280.764 us; speedup 1.0000x reference)
//
#include <hip/hip_runtime.h>
#include <stdint.h>

#define DIN 256
#define DOUT 64
#define LMAX 50
#define NEG_INF -1e9f

// ---------------------------------------------------------------------------
// Kernel 1: projection  ep[n][j] = sum_k embed[n][k] * W[j][k]
// lanes = rows: thread tid owns row (blk*256 + tid), accumulates all 64 j.
// embed staged coalesced -> LDS (stride 65, conflict-free) -> per-lane reads.
// W read with wave-uniform indices -> scalar loads (s_load_dwordx4), no LDS.
// ---------------------------------------------------------------------------
__global__ __launch_bounds__(256) void proj_kernel(
    const float* __restrict__ embed, const float* __restrict__ W,
    float* __restrict__ ep, int N)
{
    __shared__ float at[256 * 65];          // 66,560 B -> 2 blocks/CU

    const int tid   = threadIdx.x;
    const int rows0 = blockIdx.x * 256;
    const bool active = (rows0 + tid) < N;

    float acc[64];
#pragma unroll
    for (int j = 0; j < 64; ++j) acc[j] = 0.f;

    for (int kc = 0; kc < DIN; kc += 64) {
        // --- stage 256 rows x 64 k, coalesced float4 global loads ---
        // f4 = tid + 256v: r = f4/16 (16 float4 per row-chunk), c4 = f4%16.
        // LDS store banks (r + 4c4 + m)%32 -> 2-way (free).
#pragma unroll
        for (int v = 0; v < 16; ++v) {
            const int f4 = tid + v * 256;
            const int r  = f4 >> 4;
            const int c4 = f4 & 15;
            float4 val = make_float4(0.f, 0.f, 0.f, 0.f);
            if (rows0 + r < N)
                val = *(const float4*)&embed[(size_t)(rows0 + r) * DIN + kc + c4 * 4];
            float* dst = &at[r * 65 + c4 * 4];
            dst[0] = val.x; dst[1] = val.y; dst[2] = val.z; dst[3] = val.w;
        }
        __syncthreads();

        if (active) {
            const float* arow = &at[tid * 65];
#pragma unroll 4
            for (int k4 = 0; k4 < 16; ++k4) {
                // per-lane LDS reads: banks (tid + 4k4 + m)%32 -> 2-way free
                const float a0 = arow[k4 * 4 + 0];
                const float a1 = arow[k4 * 4 + 1];
                const float a2 = arow[k4 * 4 + 2];
                const float a3 = arow[k4 * 4 + 3];
                const float* wp = &W[kc + k4 * 4];
#pragma unroll
                for (int j = 0; j < 64; ++j) {
                    // wave-uniform address -> s_load_dwordx4 (scalar pipe)
                    const float4 w = *(const float4*)&wp[j * DIN];
                    acc[j] += a0 * w.x + a1 * w.y + a2 * w.z + a3 * w.w;
                }
            }
        }
        __syncthreads();
    }

    // --- epilogue: bounce acc through LDS for coalesced global stores ---
#pragma unroll
    for (int j = 0; j < 64; ++j) at[tid * 65 + j] = acc[j];   // (tid+j)%32 free
    __syncthreads();
#pragma unroll
    for (int v = 0; v < 16; ++v) {
        const int f4 = tid + v * 256;
        const int r  = f4 >> 4;
        const int j0 = (f4 & 15) * 4;
        if (rows0 + r < N) {
            float4 o;
            o.x = at[r * 65 + j0 + 0];
            o.y = at[r * 65 + j0 + 1];
            o.z = at[r * 65 + j0 + 2];
            o.w = at[r * 65 + j0 + 3];
            *(float4*)&ep[(size_t)(rows0 + r) * DOUT + j0] = o;   // coalesced
        }
    }
}

// ---------------------------------------------------------------------------
// Kernel 2: GAT attention + aggregation. 1 wave per node, 4 nodes/block.
// Gather via global_load_lds DMA into stride-64 rows (DMA requires base+lane*4).
// Phase 1 uses lane-rotated ds_read_b128 (banks balanced on stride-64).
// Attention weights broadcast via v_readlane (no LDS round trip).
// ---------------------------------------------------------------------------
__global__ __launch_bounds__(256) void agg_kernel(
    const int* __restrict__ neighs, const void* __restrict__ mask,
    const int* __restrict__ dst_idx, const float* __restrict__ ep,
    const float* __restrict__ a_src, const float* __restrict__ a_dst,
    float* __restrict__ out, int B)
{
    __shared__ float fw_all[4 * LMAX * 64];   // 51,200 B -> 3 blocks/CU
    __shared__ float asrc_lds[64];

    const int tid  = threadIdx.x;
    const int lane = tid & 63;
    const int wv   = tid >> 6;
    const int b    = blockIdx.x * 4 + wv;
    const int bc   = b < B ? b : B - 1;       // clamp (grid exact for B=50000)

    if (tid < 64) asrc_lds[tid] = a_src[tid];

    // mask storage-format detection: element 50 (row1,col0) is always True.
    const unsigned int* mw = (const unsigned int*)mask;
    const bool byteMode = (mw[12] > 1u);

    // --- dst attention BEFORE the DMAs (avoid waiting on the DMA queue) ---
    const int di = dst_idx[bc];
    float pd = ep[(size_t)di * DOUT + lane] * a_dst[lane];
#pragma unroll
    for (int m = 32; m >= 1; m >>= 1) pd += __shfl_xor(pd, m, 64);
    const float dst_attn = pd >= 0.f ? pd : 0.2f * pd;

    // per-lane neighbor mask (lane = l)
    bool mvalid = false;
    if (lane < LMAX) {
        const int mi = bc * LMAX + lane;
        mvalid = byteMode ? (((const uint8_t*)mask)[mi] != 0)
                          : (((const int*)mask)[mi] != 0);
    }

    // --- async gather: 50 rows, 256 B each, direct global->LDS DMA ---
    float* fw = fw_all + wv * (LMAX * 64);
    const int* nb = neighs + (size_t)bc * LMAX;
#pragma unroll 10
    for (int l = 0; l < LMAX; ++l) {
        const int n = nb[l];
        const float* gp = ep + (size_t)n * DOUT + lane;
        __builtin_amdgcn_global_load_lds(
            (const __attribute__((address_space(1))) void*)gp,
            (__attribute__((address_space(3))) void*)&fw[l * 64],
            4, 0, 0);
    }

    __syncthreads();   // drains DMA (vmcnt) + publishes asrc_lds

    // --- phase 1: per-row score dot, lanes = l, lane-rotated b128 reads ---
    const int r = lane < LMAX ? lane : lane - LMAX;  // spare lanes read a valid row
    const float* frow = &fw[r * 64];
    float dot = 0.f;
#pragma unroll
    for (int k4 = 0; k4 < 16; ++k4) {
        const int p = ((k4 + lane) & 15) * 4;        // rotation: banks balanced
        const float4 f = *(const float4*)&frow[p];
        const float4 s = *(const float4*)&asrc_lds[p];
        dot += f.x * s.x + f.y * s.y + f.z * s.z + f.w * s.w;
    }
    const float lr = dot >= 0.f ? dot : 0.2f * dot;
    float s = (lane < LMAX && mvalid) ? (dst_attn + lr) : NEG_INF;

    float mx = s;
#pragma unroll
    for (int m = 32; m >= 1; m >>= 1) mx = fmaxf(mx, __shfl_xor(mx, m, 64));
    const float e = __expf(s - mx);                  // masked lanes -> exactly 0
    float se = e;
#pragma unroll
    for (int m = 32; m >= 1; m >>= 1) se += __shfl_xor(se, m, 64);
    const float wgt = e / se;

    // --- phase 2: weighted sum, lanes = j; weights via v_readlane ---
    float acc = 0.f;
#pragma unroll
    for (int l = 0; l < LMAX; l += 2) {
        const float w0 = __int_as_float(__builtin_amdgcn_readlane(__float_as_int(wgt), l));
        const float w1 = __int_as_float(__builtin_amdgcn_readlane(__float_as_int(wgt), l + 1));
        acc = fmaf(w0, fw[l * 64 + lane], acc);          // banks lane%32: free
        acc = fmaf(w1, fw[(l + 1) * 64 + lane], acc);    // pairs -> ds_read2_b32
    }
    if (b < B) out[(size_t)b * DOUT + lane] = acc;
}

// ---------------------------------------------------------------------------
extern "C" void kernel_launch(void* const* d_in, const int* in_sizes, int n_in,
                              void* d_out, int out_size, void* d_ws, size_t ws_size,
                              hipStream_t stream)
{
    const int*   neighs  = (const int*)d_in[0];
    const void*  mask    = d_in[1];
    const int*   dst_idx = (const int*)d_in[2];
    const float* embed   = (const float*)d_in[3];
    const float* W       = (const float*)d_in[4];
    const float* a_src   = (const float*)d_in[5];
    const float* a_dst   = (const float*)d_in[6];
    float* out = (float*)d_out;

    const int B = in_sizes[2];            // 50000
    const int N = in_sizes[3] / DIN;      // 200000

    float* ep = (float*)d_ws;             // N * 64 * 4 = 51.2 MB scratch

    proj_kernel<<<dim3((N + 255) / 256), dim3(256), 0, stream>>>(embed, W, ep, N);
    agg_kernel<<<dim3((B + 3) / 4), dim3(256), 0, stream>>>(
        neighs, mask, dst_idx, ep, a_src, a_dst, out, B);
}

// Round 3
// 398.486 us; speedup vs baseline: 3.2141x; 3.2141x over previous
//
#include <hip/hip_runtime.h>
#include <stdint.h>

#define DIN 256
#define DOUT 64
#define LMAX 50
#define NEG_INF -1e9f

static __device__ __forceinline__ unsigned short f2bf(float x) {
    unsigned int u = __float_as_uint(x);
    u += 0x7fffu + ((u >> 16) & 1u);     // RNE
    return (unsigned short)(u >> 16);
}

// ---------------------------------------------------------------------------
// Kernel 1: projection  ep16[n][j] = bf16( sum_k embed[n][k] * W[j][k] )
// Classic register-tiled fp32 GEMM: BM=128, BN=64, BK=32, 256 threads,
// 8x4 register tile per thread. A staged transposed As[k][m] (pad 132),
// B staged Bs[k][j] (pad 68) -> compute-phase LDS reads conflict-free b128.
// ---------------------------------------------------------------------------
__global__ __launch_bounds__(256, 4) void proj_kernel(
    const float* __restrict__ embed, const float* __restrict__ W,
    unsigned short* __restrict__ ep16, int N)
{
    __shared__ float As[32 * 132];   // As[k*132 + m], 16,896 B
    __shared__ float Bs[32 * 68];    // Bs[k*68  + j],  8,704 B

    const int tid   = threadIdx.x;
    const int rows0 = blockIdx.x * 128;
    const int tx    = tid & 15;      // j0 = 4*tx
    const int ty    = tid >> 4;      // m0 = 8*ty

    float acc[8][4];
#pragma unroll
    for (int r = 0; r < 8; ++r)
#pragma unroll
        for (int c = 0; c < 4; ++c) acc[r][c] = 0.f;

    for (int kc = 0; kc < DIN; kc += 32) {
        // ---- fetch chunk to registers (before barrier) ----
        float4 av[4], bv[2];
#pragma unroll
        for (int v = 0; v < 4; ++v) {
            const int f4 = tid + 256 * v;
            const int m  = f4 >> 3;          // row within tile
            const int c  = f4 & 7;           // float4 within 32-k chunk
            av[v] = make_float4(0.f, 0.f, 0.f, 0.f);
            if (rows0 + m < N)
                av[v] = *(const float4*)&embed[(size_t)(rows0 + m) * DIN + kc + 4 * c];
        }
#pragma unroll
        for (int v = 0; v < 2; ++v) {
            const int f4 = tid + 256 * v;
            const int j  = f4 >> 3;
            const int c  = f4 & 7;
            bv[v] = *(const float4*)&W[(size_t)j * DIN + kc + 4 * c];
        }
        __syncthreads();                      // prev-chunk reads done
        // ---- store transposed into LDS ----
#pragma unroll
        for (int v = 0; v < 4; ++v) {
            const int f4 = tid + 256 * v;
            const int m  = f4 >> 3;
            const int c  = f4 & 7;
            As[(4 * c + 0) * 132 + m] = av[v].x;
            As[(4 * c + 1) * 132 + m] = av[v].y;
            As[(4 * c + 2) * 132 + m] = av[v].z;
            As[(4 * c + 3) * 132 + m] = av[v].w;
        }
#pragma unroll
        for (int v = 0; v < 2; ++v) {
            const int f4 = tid + 256 * v;
            const int j  = f4 >> 3;
            const int c  = f4 & 7;
            Bs[(4 * c + 0) * 68 + j] = bv[v].x;
            Bs[(4 * c + 1) * 68 + j] = bv[v].y;
            Bs[(4 * c + 2) * 68 + j] = bv[v].z;
            Bs[(4 * c + 3) * 68 + j] = bv[v].w;
        }
        __syncthreads();
        // ---- compute: 32 k-steps, 3 b128 LDS reads + 32 FMA each ----
#pragma unroll 4
        for (int k = 0; k < 32; ++k) {
            const float4 a0 = *(const float4*)&As[k * 132 + ty * 8];
            const float4 a1 = *(const float4*)&As[k * 132 + ty * 8 + 4];
            const float4 b4 = *(const float4*)&Bs[k * 68 + tx * 4];
            const float ar[8] = {a0.x, a0.y, a0.z, a0.w, a1.x, a1.y, a1.z, a1.w};
            const float br[4] = {b4.x, b4.y, b4.z, b4.w};
#pragma unroll
            for (int r = 0; r < 8; ++r)
#pragma unroll
                for (int c = 0; c < 4; ++c)
                    acc[r][c] = fmaf(ar[r], br[c], acc[r][c]);
        }
    }

    // ---- epilogue: bf16 convert + 8B stores (coalesced across tx) ----
#pragma unroll
    for (int r = 0; r < 8; ++r) {
        const int row = rows0 + ty * 8 + r;
        if (row < N) {
            ushort4 o;
            o.x = f2bf(acc[r][0]);
            o.y = f2bf(acc[r][1]);
            o.z = f2bf(acc[r][2]);
            o.w = f2bf(acc[r][3]);
            *(ushort4*)&ep16[(size_t)row * DOUT + tx * 4] = o;
        }
    }
}

// ---------------------------------------------------------------------------
// Kernel 2: GAT attention + aggregation. 1 wave/node, 4 nodes/block.
// ep is bf16 (row = 128 B = 32 uints). Gather via global_load_lds width=16:
// one instr = 8 rows (1 KB). Masked rows' lanes redirected to nb[0]'s row
// (always valid, same line as lanes 0-7 -> free) so LDS is fully written.
// ---------------------------------------------------------------------------
__global__ __launch_bounds__(256, 6) void agg_kernel(
    const int* __restrict__ neighs, const void* __restrict__ mask,
    const int* __restrict__ dst_idx, const unsigned int* __restrict__ ep16,
    const float* __restrict__ a_src, const float* __restrict__ a_dst,
    float* __restrict__ out, int B)
{
    __shared__ unsigned int fw_all[4 * LMAX * 32];  // 25,600 B
    __shared__ float attn_all[4 * 64];
    __shared__ float asrc_lds[64];

    const int tid  = threadIdx.x;
    const int lane = tid & 63;
    const int wv   = tid >> 6;
    const int b    = blockIdx.x * 4 + wv;
    const int bc   = b < B ? b : B - 1;
    const int c    = lane & 31;                     // column pair index

    if (tid < 64) asrc_lds[tid] = a_src[tid];

    // mask storage-format detection: flat element 50 (row1,col0) always True.
    const unsigned int* mw = (const unsigned int*)mask;
    const bool byteMode = (mw[12] > 1u);

    // per-lane neighbor mask (lane = l)
    bool mvalid = false;
    if (lane < LMAX) {
        const int mi = bc * LMAX + lane;
        mvalid = byteMode ? (((const uint8_t*)mask)[mi] != 0)
                          : (((const int*)mask)[mi] != 0);
    }
    const unsigned long long vm = __ballot(mvalid);

    const int* nb = neighs + (size_t)bc * LMAX;
    const int n0  = nb[0];                          // always valid

    // issue dst-row load early (shares vmcnt FIFO; waiting on it later
    // does NOT drain the younger DMA loads)
    const unsigned int du = ep16[(size_t)dst_idx[bc] * 32 + c];
    const float2 ad = *(const float2*)&a_dst[2 * c];

    // ---- async gather: 6 x width-16 DMA (8 rows each) + 1 x width-4 (2 rows)
    unsigned int* fw = fw_all + wv * (LMAX * 32);
#pragma unroll
    for (int i = 0; i < 6; ++i) {
        const int r = 8 * i + (lane >> 3);
        const int n = ((vm >> r) & 1ull) ? nb[r] : n0;
        const unsigned int* gp = ep16 + (size_t)n * 32 + (lane & 7) * 4;
        __builtin_amdgcn_global_load_lds(
            (const __attribute__((address_space(1))) void*)gp,
            (__attribute__((address_space(3))) void*)&fw[i * 256],
            16, 0, 0);
    }
    {   // rows 48,49: 64 lanes x 4 B = 256 B
        const int r = 48 + (lane >> 5);
        const int n = ((vm >> r) & 1ull) ? nb[r] : n0;
        const unsigned int* gp = ep16 + (size_t)n * 32 + c;
        __builtin_amdgcn_global_load_lds(
            (const __attribute__((address_space(1))) void*)gp,
            (__attribute__((address_space(3))) void*)&fw[48 * 32],
            4, 0, 0);
    }

    // ---- dst attention while DMAs fly (halves duplicate; sum = 2x dot) ----
    float pd = __uint_as_float(du << 16) * ad.x
             + __uint_as_float(du & 0xffff0000u) * ad.y;
#pragma unroll
    for (int m = 32; m >= 1; m >>= 1) pd += __shfl_xor(pd, m, 64);
    pd *= 0.5f;
    const float dst_attn = pd >= 0.f ? pd : 0.2f * pd;

    __syncthreads();   // drains DMA (vmcnt) + publishes asrc_lds

    // ---- phase 1: per-row score dot, lanes = l, rotated b32 reads ----
    const int l = lane < LMAX ? lane : lane - LMAX;
    const unsigned int* frow = fw + l * 32;
    float dot = 0.f;
#pragma unroll
    for (int k0 = 0; k0 < 32; ++k0) {
        const int q = (k0 + lane) & 31;             // bank = q: 2-way, free
        const unsigned int u = frow[q];
        const float2 a = *(const float2*)&asrc_lds[2 * q];
        dot += __uint_as_float(u << 16) * a.x
             + __uint_as_float(u & 0xffff0000u) * a.y;
    }
    const float lr = dot >= 0.f ? dot : 0.2f * dot;
    float s = (lane < LMAX && mvalid) ? (dst_attn + lr) : NEG_INF;

    float mx = s;
#pragma unroll
    for (int m = 32; m >= 1; m >>= 1) mx = fmaxf(mx, __shfl_xor(mx, m, 64));
    const float e = __expf(s - mx);                 // masked lanes -> exactly 0
    float se = e;
#pragma unroll
    for (int m = 32; m >= 1; m >>= 1) se += __shfl_xor(se, m, 64);
    attn_all[wv * 64 + lane] = e / se;              // same-wave write

    // ---- phase 2: weighted sum, 2 rows/iter, lanes = column pairs ----
    const float* attn = attn_all + wv * 64;         // same-wave read: no barrier
    float acc0 = 0.f, acc1 = 0.f;
#pragma unroll
    for (int i = 0; i < 25; ++i) {
        const int r = 2 * i + (lane >> 5);
        const unsigned int u = fw[r * 32 + c];      // bank = c: 2-way, free
        const float w = attn[r];                    // broadcast (2 addrs)
        acc0 = fmaf(w, __uint_as_float(u << 16), acc0);
        acc1 = fmaf(w, __uint_as_float(u & 0xffff0000u), acc1);
    }
    acc0 += __shfl_xor(acc0, 32, 64);               // even-rows + odd-rows half
    acc1 += __shfl_xor(acc1, 32, 64);
    if (b < B && lane < 32) {
        float2 o; o.x = acc0; o.y = acc1;
        *(float2*)&out[(size_t)b * DOUT + 2 * c] = o;
    }
}

// ---------------------------------------------------------------------------
extern "C" void kernel_launch(void* const* d_in, const int* in_sizes, int n_in,
                              void* d_out, int out_size, void* d_ws, size_t ws_size,
                              hipStream_t stream)
{
    const int*   neighs  = (const int*)d_in[0];
    const void*  mask    = d_in[1];
    const int*   dst_idx = (const int*)d_in[2];
    const float* embed   = (const float*)d_in[3];
    const float* W       = (const float*)d_in[4];
    const float* a_src   = (const float*)d_in[5];
    const float* a_dst   = (const float*)d_in[6];
    float* out = (float*)d_out;

    const int B = in_sizes[2];            // 50000
    const int N = in_sizes[3] / DIN;      // 200000

    unsigned short* ep16 = (unsigned short*)d_ws;   // N*64*2 = 25.6 MB

    proj_kernel<<<dim3((N + 127) / 128), dim3(256), 0, stream>>>(embed, W, ep16, N);
    agg_kernel<<<dim3((B + 3) / 4), dim3(256), 0, stream>>>(
        neighs, mask, dst_idx, (const unsigned int*)ep16, a_src, a_dst, out, B);
}